// Round 6
// baseline (839.701 us; speedup 1.0000x reference)
//
#include <hip/hip_runtime.h>

// QuantizedLinear M=8192 K=4096 N=11008.
// Prepass (fused): dequant int4-blockwise W -> f16 [N][K]; cvt x -> f16 [M][K].
// GEMM: 256x256 tile, BK=32, 512 thr (8 waves 2Mx4N), mfma_f32_32x32x16_f16,
// cross-phase LDS->reg prefetch (Fa/Fb ping-pong: reads for phase p+1 issue before
// MFMA of phase p -> LDS streaming overlaps matrix pipe), 3-parity A+B rings (96KB),
// ONE barrier per K-tile, lgkmcnt(0) pre-barrier (WAR-safe), vmcnt(4) boundary,
// XOR-swizzled LDS (linear gload_lds dest + pre-swizzled global src), setprio, XCD swizzle.

#define K_DIM 4096
#define N_DIM 11008
#define M_DIM 8192
#define NT 128  // K tiles of 32

typedef _Float16 f16;
typedef _Float16 f16x8 __attribute__((ext_vector_type(8)));
typedef float f32x16 __attribute__((ext_vector_type(16)));
typedef float fv4 __attribute__((ext_vector_type(4)));
typedef int iv4 __attribute__((ext_vector_type(4)));

__device__ __forceinline__ void gload16(const void* g, void* lds) {
  __builtin_amdgcn_global_load_lds(
      (__attribute__((address_space(1))) void*)g,
      (__attribute__((address_space(3))) void*)lds,
      16, 0, 0);
}

// fused prepass: threads [0,n8x) convert x (f32->f16, 8/thread); rest dequant W (8/thread).
__global__ __launch_bounds__(256) void prep_kernel(const float* __restrict__ x,
                                                   f16* __restrict__ xo, int n8x,
                                                   const int* __restrict__ q,
                                                   const float* __restrict__ amax,
                                                   f16* __restrict__ wo, int n8w) {
  int i = blockIdx.x * blockDim.x + threadIdx.x;
  if (i < n8x) {
    const fv4* xv = (const fv4*)x;
    fv4 a = __builtin_nontemporal_load(xv + 2 * (size_t)i);
    fv4 b = __builtin_nontemporal_load(xv + 2 * (size_t)i + 1);
    f16x8 o;
    o[0] = (f16)a.x; o[1] = (f16)a.y; o[2] = (f16)a.z; o[3] = (f16)a.w;
    o[4] = (f16)b.x; o[5] = (f16)b.y; o[6] = (f16)b.z; o[7] = (f16)b.w;
    *(f16x8*)(xo + (size_t)i * 8) = o;
  } else {
    int j = i - n8x;
    if (j >= n8w) return;
    const iv4* qv = (const iv4*)q;
    iv4 a = __builtin_nontemporal_load(qv + 2 * (size_t)j);
    iv4 b = __builtin_nontemporal_load(qv + 2 * (size_t)j + 1);
    float s = amax[j >> 3] * (1.0f / 7.0f);
    f16x8 o;
    o[0] = (f16)((float)a.x * s); o[1] = (f16)((float)a.y * s);
    o[2] = (f16)((float)a.z * s); o[3] = (f16)((float)a.w * s);
    o[4] = (f16)((float)b.x * s); o[5] = (f16)((float)b.y * s);
    o[6] = (f16)((float)b.z * s); o[7] = (f16)((float)b.w * s);
    *(f16x8*)(wo + (size_t)j * 8) = o;
  }
}

// LDS: A ring 3 x 16KB at 0/16K/32K; B ring 3 x 16KB at 48K/64K/80K. Slot = 256 rows x 32 f16
// stored [128 ldsrows][128B], swizzle: pos(ra,kb): r=ra>>1, c=(((ra&1)<<6)|kb)^((r&7)<<4).
// Tile t reads slots t%3; stages A[t+2] (ph0) and B[t+2] (ph1) into slot (t+2)%3.
// Boundary (in ph1): lgkmcnt(0); vmcnt(4) confirms tile t+1; barrier; prefetch t+1 ph0 frags.
__global__ __launch_bounds__(512, 2) void gemm_f16_bt(const f16* __restrict__ A,
                                                      const f16* __restrict__ B,
                                                      const float* __restrict__ bias,
                                                      float* __restrict__ C) {
  __shared__ __align__(16) char lds[98304];

  const int tid = threadIdx.x;
  const int w = tid >> 6;
  const int l = tid & 63;
  const int wr = w >> 2;  // 0..1 : 128 M-rows each
  const int wc = w & 3;   // 0..3 : 64 N-cols each

  // bijective XCD swizzle: nwg = 1376 = 8 * 172
  const int wg = blockIdx.x;
  const int swz = (wg & 7) * 172 + (wg >> 3);
  const int mt = swz / 43;
  const int nt = swz % 43;
  const int m0 = mt * 256;
  const int n0 = nt * 256;

  // 32x32 fragment lane terms: ra = R0 + (l&31), kb = ks*32 + (l>>5)*16
  const int l31 = l & 31;
  const int lbase = (l31 >> 1) << 7;
  const int lxor = ((l31 >> 1) & 7) << 4;
  const int lk = ((l & 1) << 6) | ((l >> 5) << 4);
  const int lt0 = lk ^ lxor;          // ks = 0
  const int lt1 = (lk | 32) ^ lxor;   // ks = 1

  // pre-swizzled staging sources: wave w stages 1KB chunks w and w+8 of each 16KB slot
  const char* AsrcP[2];
  const char* BsrcP[2];
#pragma unroll
  for (int j = 0; j < 2; ++j) {
    const int u = ((w + j * 8) << 10) + l * 16;
    const int r = u >> 7;
    const int cp = (u & 127) ^ ((r & 7) << 4);
    const int ra = 2 * r + (cp >> 6);
    const int kb = cp & 63;
    AsrcP[j] = (const char*)A + (size_t)(m0 + ra) * (K_DIM * 2) + kb;
    BsrcP[j] = (const char*)B + (size_t)(n0 + ra) * (K_DIM * 2) + kb;
  }

  char* ldsc = (char*)lds;

#define STAGE_A(slot, koff)                          \
  {                                                  \
    char* d_ = ldsc + (slot) + w * 1024;             \
    gload16(AsrcP[0] + (koff), d_);                  \
    gload16(AsrcP[1] + (koff), d_ + 8192);           \
  }
#define STAGE_B(slot, koff)                          \
  {                                                  \
    char* d_ = ldsc + (slot) + w * 1024;             \
    gload16(BsrcP[0] + (koff), d_);                  \
    gload16(BsrcP[1] + (koff), d_ + 8192);           \
  }

  f32x16 acc[4][2];
#pragma unroll
  for (int i = 0; i < 4; ++i)
#pragma unroll
    for (int j = 0; j < 2; ++j) acc[i][j] = (f32x16)0.f;

  const int aW = wr * 8192;  // (wr*128)*64
  const int bW = wc * 4096;  // (wc*64)*64

  // prologue: stage tiles 0,1 (8 gloads/wave)
  STAGE_A(0, 0);
  STAGE_B(49152, 0);
  STAGE_A(16384, 64);
  STAGE_B(49152 + 16384, 64);
  asm volatile("s_waitcnt vmcnt(4)" ::: "memory");  // tile 0 landed
  __builtin_amdgcn_s_barrier();

  int aCur = 0, aNxt = 16384, aNx2 = 32768;
  int bCur = 49152, bNxt = 65536, bNx2 = 81920;

  f16x8 afa[4], bfa[2], afb[4], bfb[2];
  // prefetch tile 0 phase 0 (ks=0)
#pragma unroll
  for (int mf = 0; mf < 4; ++mf)
    afa[mf] = *(const f16x8*)(ldsc + aCur + aW + mf * 2048 + lbase + lt0);
#pragma unroll
  for (int nf = 0; nf < 2; ++nf)
    bfa[nf] = *(const f16x8*)(ldsc + bCur + bW + nf * 2048 + lbase + lt0);

  for (int t = 0; t < NT; ++t) {
    const int t2 = (t + 2 < NT) ? (t + 2) : (NT - 1);
    const int k2 = t2 * 64;  // byte k-offset (32 f16 per row per tile)

    // ---- phase 0: consume Fa (ks=0); prefetch Fb (ks=1, same tile); stage A[t+2]
    STAGE_A(aNx2, k2);
#pragma unroll
    for (int mf = 0; mf < 4; ++mf)
      afb[mf] = *(const f16x8*)(ldsc + aCur + aW + mf * 2048 + lbase + lt1);
#pragma unroll
    for (int nf = 0; nf < 2; ++nf)
      bfb[nf] = *(const f16x8*)(ldsc + bCur + bW + nf * 2048 + lbase + lt1);
    __builtin_amdgcn_s_setprio(1);
#pragma unroll
    for (int mf = 0; mf < 4; ++mf)
#pragma unroll
      for (int nf = 0; nf < 2; ++nf)
        acc[mf][nf] = __builtin_amdgcn_mfma_f32_32x32x16_f16(afa[mf], bfa[nf], acc[mf][nf], 0, 0, 0);
    __builtin_amdgcn_s_setprio(0);

    // ---- phase 1: consume Fb; stage B[t+2]; tile boundary; prefetch Fa (tile t+1, ks=0)
    STAGE_B(bNx2, k2);
    asm volatile("s_waitcnt lgkmcnt(0)" ::: "memory");  // all my LDS reads done (WAR-safe)
    asm volatile("s_waitcnt vmcnt(4)" ::: "memory");    // tile t+1 fully in LDS
    __builtin_amdgcn_s_barrier();
#pragma unroll
    for (int mf = 0; mf < 4; ++mf)
      afa[mf] = *(const f16x8*)(ldsc + aNxt + aW + mf * 2048 + lbase + lt0);
#pragma unroll
    for (int nf = 0; nf < 2; ++nf)
      bfa[nf] = *(const f16x8*)(ldsc + bNxt + bW + nf * 2048 + lbase + lt0);
    __builtin_amdgcn_s_setprio(1);
#pragma unroll
    for (int mf = 0; mf < 4; ++mf)
#pragma unroll
      for (int nf = 0; nf < 2; ++nf)
        acc[mf][nf] = __builtin_amdgcn_mfma_f32_32x32x16_f16(afb[mf], bfb[nf], acc[mf][nf], 0, 0, 0);
    __builtin_amdgcn_s_setprio(0);

    const int ta = aCur; aCur = aNxt; aNxt = aNx2; aNx2 = ta;
    const int tb = bCur; bCur = bNxt; bNxt = bNx2; bNx2 = tb;
  }

  // epilogue: 32x32 C/D layout col = lane&31, row = (reg&3) + 8*(reg>>2) + 4*(lane>>5)
  const int rbase = 4 * (l >> 5);
  float bv[2];
#pragma unroll
  for (int nf = 0; nf < 2; ++nf) bv[nf] = bias[n0 + wc * 64 + nf * 32 + l31];
#pragma unroll
  for (int mf = 0; mf < 4; ++mf) {
#pragma unroll
    for (int nf = 0; nf < 2; ++nf) {
      const size_t col = n0 + wc * 64 + nf * 32 + l31;
#pragma unroll
      for (int q = 0; q < 4; ++q) {
#pragma unroll
        for (int j = 0; j < 4; ++j) {
          const int row = m0 + wr * 128 + mf * 32 + rbase + 8 * q + j;
          __builtin_nontemporal_store(acc[mf][nf][q * 4 + j] + bv[nf],
                                      &C[(size_t)row * N_DIM + col]);
        }
      }
    }
  }
#undef STAGE_A
#undef STAGE_B
}

extern "C" void kernel_launch(void* const* d_in, const int* in_sizes, int n_in,
                              void* d_out, int out_size, void* d_ws, size_t ws_size,
                              hipStream_t stream) {
  const float* x = (const float*)d_in[0];
  const int* wq = (const int*)d_in[1];
  const float* amax = (const float*)d_in[2];
  const float* bias = (const float*)d_in[3];
  float* out = (float*)d_out;

  f16* Xh = (f16*)d_ws;                                       // 64 MB
  f16* Wh = (f16*)((char*)d_ws + (size_t)M_DIM * K_DIM * 2);  // 90 MB

  {
    int n8x = M_DIM * K_DIM / 8;  // 4194304 (multiple of 256 -> no mixed block)
    int n8w = N_DIM * K_DIM / 8;  // 5636096
    int nthr = n8x + n8w;
    prep_kernel<<<(nthr + 255) / 256, 256, 0, stream>>>(x, Xh, n8x, wq, amax, Wh, n8w);
  }
  {
    dim3 grid((M_DIM / 256) * (N_DIM / 256));  // 32*43 = 1376
    gemm_f16_bt<<<grid, 512, 0, stream>>>(Xh, Wh, bias, out);
  }
}